// Round 4
// baseline (4886.919 us; speedup 1.0000x reference)
//
#include <hip/hip_runtime.h>
#include <hip/hip_bf16.h>
#include <math.h>

// LSTM greedy decoder — single persistent kernel for all 20 steps.
// R3: R2 showed every per-step kernel < 40us; ~800us of the 1337us total is
// serial launch/gap overhead of 81 dependent dispatches. Fuse the whole
// recurrence into one 256-block x 512-thread persistent kernel with
// device-scope atomic grid barriers (one-shot counters, zeroed by init each
// call; agent-scope __hip_atomic_* per XCD-coherence rules).
//   P1 gates: fp32 VALU (recurrence precision), 8x8 thread tiles, K-split 16.
//   P2 cell:  partial-sum + activations; emits hT [k][b], h hi/lo bf16 [b][k],
//             h_bk fp32 [b][k] for the exact recompute.
//   P3 logits: MFMA 16x16x32 bf16, 3-term split (hh+hl+lh); 4 fat waves x 32n
//             per block (halves per-CU A-frag LDS re-reads vs 8 waves x 16n);
//             per-wave top-2 sortable keys.
//   P4: global top-2 -> EXACT fp32 recompute (bit-identical structure to R2,
//             which measured absmax 0.0) -> outputs + embedding gather.
// Co-residency: grid=256, <=64KB LDS, launch_bounds(512,2) -> >=1 block/CU
// capacity on 256 CUs, so all blocks resident; barriers safe.

#define B 128
#define E 512
#define H 512
#define V 32000
#define TSEQ 20
#define NG 2048            // 4*H
#define KSPLIT 16
#define GRID 256
#define NBLK_L 250         // 32000 / 128
#define WTILES 1000        // 250 blocks * 4 fat waves
#define WTPAD 1024

typedef __attribute__((ext_vector_type(8))) short short8v;
typedef __attribute__((ext_vector_type(4))) float f32x4;
typedef unsigned long long ull;

__device__ __forceinline__ float sigmoidf_(float x) { return 1.0f / (1.0f + expf(-x)); }

__device__ __forceinline__ short f2bf_s(float x) {
    __hip_bfloat16 h = __float2bfloat16(x);
    return *reinterpret_cast<short*>(&h);
}
__device__ __forceinline__ float bfs2f(short s) {
    __hip_bfloat16 h = *reinterpret_cast<__hip_bfloat16*>(&s);
    return __bfloat162float(h);
}
__device__ __forceinline__ ull shflx_u64(ull x, int m) {
    int lo = __shfl_xor((int)(unsigned int)x, m);
    int hi = __shfl_xor((int)(unsigned int)(x >> 32), m);
    return ((ull)(unsigned int)hi << 32) | (unsigned int)lo;
}
__device__ __forceinline__ void merge2(ull& k1, ull& k2, ull o1, ull o2) {
    ull a = k1 > o1 ? k1 : o1;
    ull b = k1 > o1 ? o1 : k1;
    ull c = k2 > o2 ? k2 : o2;
    k1 = a;
    k2 = b > c ? b : c;
}
__device__ __forceinline__ ull makekey(float v, unsigned int n) {
    unsigned int u = __float_as_uint(v);
    u ^= (unsigned int)(((int)u >> 31)) | 0x80000000u;
    return ((ull)u << 32) | (0xFFFFFFFFu - n);
}
__device__ __forceinline__ int keyidx(ull k) {
    return (int)(0xFFFFFFFFu - (unsigned int)(k & 0xFFFFFFFFu));
}

// device-scope one-shot grid barrier (cnt[id] zeroed by init each launch)
__device__ __forceinline__ void gridbar(unsigned* cnt, int id) {
    __syncthreads();
    if (threadIdx.x == 0) {
        unsigned* c = cnt + id;
        __hip_atomic_fetch_add(c, 1u, __ATOMIC_ACQ_REL, __HIP_MEMORY_SCOPE_AGENT);
        while (__hip_atomic_load(c, __ATOMIC_ACQUIRE, __HIP_MEMORY_SCOPE_AGENT) < GRID) {
            __builtin_amdgcn_s_sleep(2);
        }
    }
    __syncthreads();
}

// ---- W_fc fp32 -> bf16 hi/lo split ----------------------------------------
__global__ __launch_bounds__(256) void wsplit_kernel(const float* __restrict__ W,
                                                     short* __restrict__ Wh,
                                                     short* __restrict__ Wl) {
    size_t i = ((size_t)blockIdx.x * 256 + threadIdx.x) * 8;
    float4 a = *reinterpret_cast<const float4*>(W + i);
    float4 b = *reinterpret_cast<const float4*>(W + i + 4);
    float xv[8] = {a.x, a.y, a.z, a.w, b.x, b.y, b.z, b.w};
    union { short8v v; short s[8]; } uh, ul;
#pragma unroll
    for (int j = 0; j < 8; ++j) {
        short hs = f2bf_s(xv[j]);
        uh.s[j] = hs;
        ul.s[j] = f2bf_s(xv[j] - bfs2f(hs));
    }
    *reinterpret_cast<short8v*>(Wh + i) = uh.v;
    *reinterpret_cast<short8v*>(Wl + i) = ul.v;
}

// ---- init: features -> xT, zero hT/cT, zero barrier counters ---------------
__global__ __launch_bounds__(256) void init_kernel(const float* __restrict__ features,
                                                   float* __restrict__ xT,
                                                   float* __restrict__ hT,
                                                   float* __restrict__ cT,
                                                   unsigned* __restrict__ cnt) {
    int g = blockIdx.x * 256 + threadIdx.x;   // 0..65535
    int j = g >> 7, b = g & 127;
    xT[g] = features[b * E + j];
    hT[g] = 0.0f;
    cT[g] = 0.0f;
    if (g < 128) cnt[g] = 0u;
}

// ---- the persistent decoder -------------------------------------------------
__global__ __launch_bounds__(512, 2) void decode_persistent(
        float* __restrict__ xT, float* __restrict__ hT, float* __restrict__ cT,
        float* __restrict__ pT,
        short* __restrict__ h_hi, short* __restrict__ h_lo, float* __restrict__ h_bk,
        const float* __restrict__ W_ih, const float* __restrict__ W_hh,
        const float* __restrict__ b_ih, const float* __restrict__ b_hh,
        const short* __restrict__ W_hi, const short* __restrict__ W_lo,
        const float* __restrict__ W_fc, const float* __restrict__ b_fc,
        const float* __restrict__ emb,
        ull* __restrict__ pk1, ull* __restrict__ pk2,
        unsigned* __restrict__ cnt, float* __restrict__ out) {
    const int bid = blockIdx.x;
    const int tid = threadIdx.x;
    __shared__ union {
        struct { float xs[64][128]; float ws[128][64]; } p1;   // 64 KB
        short lh[2][128 * 64];                                 // 32 KB
        struct { ull k1[8]; ull k2[8]; float part[8]; int i1, i2, widx; } p4;
    } sm;

    int barid = 0;
    for (int t = 0; t < TSEQ; ++t) {
        // ================= P1: gates partials (fp32) =================
        {
            const int ntile = bid & 15;          // 128 n per tile
            const int ks = bid >> 4;             // 64 k per split
            const int kb = ks * 64;
            const bool isX = kb < E;
            const float* __restrict__ src = isX ? (xT + (size_t)kb * B)
                                                : (hT + (size_t)(kb - E) * B);
            // stage xs[k][b]: 2048 float4, 4 per thread
#pragma unroll
            for (int i = 0; i < 4; ++i) {
                int flat = i * 512 + tid;
                int kk = flat >> 5, b4 = flat & 31;
                *reinterpret_cast<float4*>(&sm.p1.xs[kk][b4 * 4]) =
                    *reinterpret_cast<const float4*>(src + kk * B + b4 * 4);
            }
            // stage ws[n][k] swizzled (slot s stored at s ^ (r>>3)): 4 f4/thread
            {
                int r = tid >> 2, q = tid & 3;
                int nglob = ntile * 128 + r;
                int jrow = nglob >> 2, g = nglob & 3;
                const float* __restrict__ Wp = isX ? (W_ih + (size_t)(g * H + jrow) * E + kb)
                                                   : (W_hh + (size_t)(g * H + jrow) * H + (kb - E));
#pragma unroll
                for (int c = 0; c < 4; ++c) {
                    int slot = (q * 4 + c) ^ (r >> 3);
                    *reinterpret_cast<float4*>(&sm.p1.ws[r][slot * 4]) =
                        *reinterpret_cast<const float4*>(Wp + q * 16 + c * 4);
                }
            }
            __syncthreads();
            if (tid < 256) {   // waves 0-3 compute 8x8 tiles
                const int nt = tid & 15;   // n0 = nt*8
                const int bt = tid >> 4;   // b0 = bt*8
                float acc[8][8];
#pragma unroll
                for (int i = 0; i < 8; ++i)
#pragma unroll
                    for (int j = 0; j < 8; ++j) acc[i][j] = 0.0f;
                for (int k4 = 0; k4 < 16; ++k4) {
                    float wr[8][4];
#pragma unroll
                    for (int ni = 0; ni < 8; ++ni) {
                        int slot = k4 ^ nt;
                        *reinterpret_cast<float4*>(wr[ni]) =
                            *reinterpret_cast<const float4*>(&sm.p1.ws[nt * 8 + ni][slot * 4]);
                    }
#pragma unroll
                    for (int kk = 0; kk < 4; ++kk) {
                        int k = k4 * 4 + kk;
                        float4 x0 = *reinterpret_cast<const float4*>(&sm.p1.xs[k][bt * 8]);
                        float4 x1 = *reinterpret_cast<const float4*>(&sm.p1.xs[k][bt * 8 + 4]);
                        float xr[8] = {x0.x, x0.y, x0.z, x0.w, x1.x, x1.y, x1.z, x1.w};
#pragma unroll
                        for (int bi = 0; bi < 8; ++bi)
#pragma unroll
                            for (int ni = 0; ni < 8; ++ni) acc[bi][ni] += xr[bi] * wr[ni][kk];
                    }
                }
#pragma unroll
                for (int ni = 0; ni < 8; ++ni) {
                    size_t n = (size_t)ks * NG + ntile * 128 + nt * 8 + ni;
#pragma unroll
                    for (int b4 = 0; b4 < 2; ++b4) {
                        float4 col = make_float4(acc[b4 * 4 + 0][ni], acc[b4 * 4 + 1][ni],
                                                 acc[b4 * 4 + 2][ni], acc[b4 * 4 + 3][ni]);
                        *reinterpret_cast<float4*>(&pT[n * B + bt * 8 + b4 * 4]) = col;
                    }
                }
            }
        }
        gridbar(cnt, barid++);
        // ================= P2: cell =================
        if (bid < 128) {
            const int b = tid & 127;
            const int j = bid * 4 + (tid >> 7);
            float gs[4];
#pragma unroll
            for (int g = 0; g < 4; ++g) {
                float s = b_ih[g * H + j] + b_hh[g * H + j];
#pragma unroll
                for (int ks = 0; ks < KSPLIT; ++ks)
                    s += pT[((size_t)ks * NG + 4 * j + g) * B + b];
                gs[g] = s;
            }
            float ig = sigmoidf_(gs[0]);
            float fg = sigmoidf_(gs[1]);
            float gg = tanhf(gs[2]);
            float og = sigmoidf_(gs[3]);
            float c = fg * cT[j * B + b] + ig * gg;
            cT[j * B + b] = c;
            float h = og * tanhf(c);
            hT[j * B + b] = h;
            h_bk[b * 512 + j] = h;
            short hs = f2bf_s(h);
            h_hi[b * 512 + j] = hs;
            h_lo[b * 512 + j] = f2bf_s(h - bfs2f(hs));
        }
        gridbar(cnt, barid++);
        // ================= P3: logits MFMA + per-wave top-2 =================
        if (bid < NBLK_L) {
            const int w = tid >> 6;          // wave 0..7; 0-3 compute
            const int l = tid & 63;
            const int l15 = l & 15, lg = l >> 4;
            const int n0 = bid * 128 + w * 32;   // fat wave: 32 n
            f32x4 acc[8][2];
#pragma unroll
            for (int mt = 0; mt < 8; ++mt)
#pragma unroll
                for (int ns = 0; ns < 2; ++ns) acc[mt][ns] = (f32x4){0.f, 0.f, 0.f, 0.f};
            for (int cc = 0; cc < 8; ++cc) {
                const int kb = cc * 64;
                __syncthreads();
                // stage h chunk hi+lo, swizzled 16B slots (all 8 waves)
#pragma unroll
                for (int i = 0; i < 2; ++i) {
                    int flat = tid + i * 512;
                    int row = flat >> 3, c = flat & 7;
                    int dst = row * 64 + ((c ^ (row & 7)) << 3);
                    *reinterpret_cast<short8v*>(&sm.lh[0][dst]) =
                        *reinterpret_cast<const short8v*>(&h_hi[row * 512 + kb + c * 8]);
                    *reinterpret_cast<short8v*>(&sm.lh[1][dst]) =
                        *reinterpret_cast<const short8v*>(&h_lo[row * 512 + kb + c * 8]);
                }
                __syncthreads();
                if (w < 4) {
                    short8v bh[2][2], bl[2][2];
#pragma unroll
                    for (int ns = 0; ns < 2; ++ns) {
                        int nr = n0 + ns * 16 + l15;
#pragma unroll
                        for (int ks2 = 0; ks2 < 2; ++ks2) {
                            size_t off = (size_t)nr * 512 + kb + ks2 * 32 + lg * 8;
                            bh[ns][ks2] = *reinterpret_cast<const short8v*>(&W_hi[off]);
                            bl[ns][ks2] = *reinterpret_cast<const short8v*>(&W_lo[off]);
                        }
                    }
#pragma unroll
                    for (int ks2 = 0; ks2 < 2; ++ks2) {
#pragma unroll
                        for (int mt = 0; mt < 8; ++mt) {
                            int row = mt * 16 + l15;
                            int cslot = ks2 * 4 + lg;
                            int off = row * 64 + ((cslot ^ (row & 7)) << 3);
                            short8v ah = *reinterpret_cast<const short8v*>(&sm.lh[0][off]);
                            short8v al = *reinterpret_cast<const short8v*>(&sm.lh[1][off]);
#pragma unroll
                            for (int ns = 0; ns < 2; ++ns) {
                                acc[mt][ns] = __builtin_amdgcn_mfma_f32_16x16x32_bf16(ah, bh[ns][ks2], acc[mt][ns], 0, 0, 0);
                                acc[mt][ns] = __builtin_amdgcn_mfma_f32_16x16x32_bf16(ah, bl[ns][ks2], acc[mt][ns], 0, 0, 0);
                                acc[mt][ns] = __builtin_amdgcn_mfma_f32_16x16x32_bf16(al, bh[ns][ks2], acc[mt][ns], 0, 0, 0);
                            }
                        }
                    }
                }
            }
            if (w < 4) {
                const int nr0 = n0 + l15;
                const int nr1 = n0 + 16 + l15;
                const float bias0 = b_fc[nr0];
                const float bias1 = b_fc[nr1];
                const int wt = bid * 4 + w;
#pragma unroll
                for (int mt = 0; mt < 8; ++mt) {
#pragma unroll
                    for (int r = 0; r < 4; ++r) {
                        ull k1 = makekey(acc[mt][0][r] + bias0, (unsigned)nr0);
                        ull k2 = 0;
                        merge2(k1, k2, makekey(acc[mt][1][r] + bias1, (unsigned)nr1), 0);
#pragma unroll
                        for (int off = 1; off < 16; off <<= 1) {
                            ull o1 = shflx_u64(k1, off);
                            ull o2 = shflx_u64(k2, off);
                            merge2(k1, k2, o1, o2);
                        }
                        if (l15 == 0) {
                            int brow = mt * 16 + lg * 4 + r;
                            pk1[(size_t)brow * WTPAD + wt] = k1;
                            pk2[(size_t)brow * WTPAD + wt] = k2;
                        }
                    }
                }
            }
        }
        gridbar(cnt, barid++);
        // ===== P4: global top-2 -> exact recompute -> outputs + gather =====
        if (bid < B) {
            const int b = bid;
            ull k1 = 0, k2 = 0;
            merge2(k1, k2, pk1[(size_t)b * WTPAD + tid], pk2[(size_t)b * WTPAD + tid]);
            if (tid + 512 < WTILES)
                merge2(k1, k2, pk1[(size_t)b * WTPAD + tid + 512], pk2[(size_t)b * WTPAD + tid + 512]);
#pragma unroll
            for (int off = 1; off < 64; off <<= 1)
                merge2(k1, k2, shflx_u64(k1, off), shflx_u64(k2, off));
            if ((tid & 63) == 0) { sm.p4.k1[tid >> 6] = k1; sm.p4.k2[tid >> 6] = k2; }
            __syncthreads();
            if (tid == 0) {
                k1 = sm.p4.k1[0]; k2 = sm.p4.k2[0];
#pragma unroll
                for (int wv = 1; wv < 8; ++wv) merge2(k1, k2, sm.p4.k1[wv], sm.p4.k2[wv]);
                sm.p4.i1 = keyidx(k1);
                sm.p4.i2 = keyidx(k2);
            }
            __syncthreads();
            const int i1 = sm.p4.i1, i2 = sm.p4.i2;
            if (tid < 256) {   // exact fp32 dots, bit-identical structure to R2
                const int wv = tid >> 6, l = tid & 63;
                const int idx = (wv >> 1) ? i2 : i1;
                const int k0 = (wv & 1) * 256 + l * 4;
                float s = 0.0f;
#pragma unroll
                for (int kk = 0; kk < 4; ++kk)
                    s += h_bk[(size_t)b * 512 + k0 + kk] * W_fc[(size_t)idx * E + k0 + kk];
#pragma unroll
                for (int off = 1; off < 64; off <<= 1) s += __shfl_xor(s, off);
                if (l == 0) sm.p4.part[wv] = s;
            }
            __syncthreads();
            if (tid == 0) {
                float v0 = sm.p4.part[0] + sm.p4.part[1] + b_fc[i1];
                float v1 = sm.p4.part[2] + sm.p4.part[3] + b_fc[i2];
                int wi; float wvv;
                if (v1 > v0 || (v1 == v0 && i2 < i1)) { wi = i2; wvv = v1; }
                else { wi = i1; wvv = v0; }
                out[b * TSEQ + t] = (float)wi;
                out[B * TSEQ + b * TSEQ + t] = wvv;
                sm.p4.widx = wi;
            }
            __syncthreads();
            xT[(size_t)tid * B + b] = emb[(size_t)sm.p4.widx * E + tid];
        }
        gridbar(cnt, barid++);
    }
}

// ============================================================================
extern "C" void kernel_launch(void* const* d_in, const int* in_sizes, int n_in,
                              void* d_out, int out_size, void* d_ws, size_t ws_size,
                              hipStream_t stream) {
    const float* features = (const float*)d_in[0];
    // d_in[1] = lengths: unused (fixed-length scan)
    const float* emb  = (const float*)d_in[2];
    const float* W_ih = (const float*)d_in[3];
    const float* W_hh = (const float*)d_in[4];
    const float* b_ih = (const float*)d_in[5];
    const float* b_hh = (const float*)d_in[6];
    const float* W_fc = (const float*)d_in[7];
    const float* b_fc = (const float*)d_in[8];
    float* out = (float*)d_out;

    char* p = (char*)d_ws;
    short* W_hi = (short*)p;      p += (size_t)V * E * 2;       // 32.77 MB
    short* W_lo = (short*)p;      p += (size_t)V * E * 2;       // 32.77 MB
    ull* pk1 = (ull*)p;           p += (size_t)B * WTPAD * 8;   // 1 MB
    ull* pk2 = (ull*)p;           p += (size_t)B * WTPAD * 8;   // 1 MB
    float* xT = (float*)p;        p += (size_t)E * B * 4;
    float* hT = (float*)p;        p += (size_t)E * B * 4;
    float* cT = (float*)p;        p += (size_t)E * B * 4;
    float* pT = (float*)p;        p += (size_t)KSPLIT * NG * B * 4;  // 16.78 MB
    short* h_hi = (short*)p;      p += (size_t)E * B * 2;
    short* h_lo = (short*)p;      p += (size_t)E * B * 2;
    float* h_bk = (float*)p;      p += (size_t)E * B * 4;
    unsigned* cnt = (unsigned*)p; p += 512;

    wsplit_kernel<<<8000, 256, 0, stream>>>(W_fc, W_hi, W_lo);
    init_kernel<<<256, 256, 0, stream>>>(features, xT, hT, cT, cnt);
    decode_persistent<<<GRID, 512, 0, stream>>>(
        xT, hT, cT, pT, h_hi, h_lo, h_bk,
        W_ih, W_hh, b_ih, b_hh, W_hi, W_lo, W_fc, b_fc, emb,
        pk1, pk2, cnt, out);
}

// Round 5
// 1297.169 us; speedup vs baseline: 3.7674x; 3.7674x over previous
//
#include <hip/hip_runtime.h>
#include <hip/hip_bf16.h>
#include <math.h>

// LSTM greedy decoder — R4: revert to the proven R2 multi-kernel structure
// (R3 persistent-kernel regressed 3.6x: W re-streamed from HBM at 448 GB/s
// under barrier serialization; launch gaps measured ~0 so fusion buys nothing).
// R4 deltas vs R2, all bitwise-preserving on outputs:
//  1. W_fc hi/lo packed in MFMA-fragment-linear order -> logits B-loads are
//     fully coalesced 1KB/instr (R2 did 16x64B scattered segments ~1.5TB/s).
//  2. logits: 4 fat compute waves x 32n (halves per-CU LDS A-frag reads),
//     all 8 waves stage with register prefetch; per-block top-2 LDS merge
//     -> pk partials shrink 8x, written [b][block] for coalesced argmax.
//  3. cell also emits h_bk[b][k] so argmax's exact fp32 recompute reads
//     coalesced (same values, same summation tree => same bits).

#define B 128
#define E 512
#define H 512
#define V 32000
#define TSEQ 20
#define NG 2048            // 4*H
#define KSPLIT 16
#define NBLK_L 250         // 32000 / 128
#define PKPAD 256          // padded per-b partial count (250 used)

typedef __attribute__((ext_vector_type(8))) short short8v;
typedef __attribute__((ext_vector_type(4))) float f32x4;
typedef unsigned long long ull;

__device__ __forceinline__ float sigmoidf_(float x) { return 1.0f / (1.0f + expf(-x)); }

__device__ __forceinline__ short f2bf_s(float x) {
    __hip_bfloat16 h = __float2bfloat16(x);
    return *reinterpret_cast<short*>(&h);
}
__device__ __forceinline__ float bfs2f(short s) {
    __hip_bfloat16 h = *reinterpret_cast<__hip_bfloat16*>(&s);
    return __bfloat162float(h);
}
__device__ __forceinline__ ull shflx_u64(ull x, int m) {
    int lo = __shfl_xor((int)(unsigned int)x, m);
    int hi = __shfl_xor((int)(unsigned int)(x >> 32), m);
    return ((ull)(unsigned int)hi << 32) | (unsigned int)lo;
}
// keep (k1,k2) = top-2 keys; merge with another sorted pair (o1,o2)
__device__ __forceinline__ void merge2(ull& k1, ull& k2, ull o1, ull o2) {
    ull a = k1 > o1 ? k1 : o1;
    ull b = k1 > o1 ? o1 : k1;
    ull c = k2 > o2 ? k2 : o2;
    k1 = a;
    k2 = b > c ? b : c;
}
// sortable key: high 32 = monotonic float bits, low 32 = ~n (max v, then min n)
__device__ __forceinline__ ull makekey(float v, unsigned int n) {
    unsigned int u = __float_as_uint(v);
    u ^= (unsigned int)(((int)u >> 31)) | 0x80000000u;
    return ((ull)u << 32) | (0xFFFFFFFFu - n);
}
__device__ __forceinline__ int keyidx(ull k) {
    return (int)(0xFFFFFFFFu - (unsigned int)(k & 0xFFFFFFFFu));
}

// ---- W_fc fp32 -> bf16 hi/lo split, packed MFMA-fragment-linear ------------
// elem (n,k) -> off = (((nt*8+cc)*2+ks2)*64 + lg*16+l15)*8 + e  where
// nt=n>>4, l15=n&15, cc=k>>6, ks2=(k>>5)&1, lg=(k>>3)&3, e=k&7.
// A wave's B-frag load (lane l) is then one coalesced b128 at
// (((nt*8+cc)*2+ks2)*64 + l)*8.
__global__ __launch_bounds__(256) void wsplit_pack_kernel(const float* __restrict__ W,
                                                          short* __restrict__ Wph,
                                                          short* __restrict__ Wpl) {
    size_t gid = (size_t)blockIdx.x * 256 + threadIdx.x;   // 8000*256 threads
    size_t i = gid * 8;                                    // 8 consecutive k of one n
    int n = (int)(i >> 9);
    int k0 = (int)(i & 511);
    float4 a = *reinterpret_cast<const float4*>(W + i);
    float4 b = *reinterpret_cast<const float4*>(W + i + 4);
    float xv[8] = {a.x, a.y, a.z, a.w, b.x, b.y, b.z, b.w};
    union { short8v v; short s[8]; } uh, ul;
#pragma unroll
    for (int j = 0; j < 8; ++j) {
        short hs = f2bf_s(xv[j]);
        uh.s[j] = hs;
        ul.s[j] = f2bf_s(xv[j] - bfs2f(hs));
    }
    int nt = n >> 4, l15 = n & 15, cc = k0 >> 6, ks2 = (k0 >> 5) & 1, lg = (k0 >> 3) & 3;
    int lane = lg * 16 + l15;
    size_t off = ((((size_t)nt * 8 + cc) * 2 + ks2) * 64 + lane) * 8;
    *reinterpret_cast<short8v*>(Wph + off) = uh.v;
    *reinterpret_cast<short8v*>(Wpl + off) = ul.v;
}

// ---- init: features -> xT (transposed), zero hT/cT -------------------------
__global__ __launch_bounds__(256) void init_kernel(const float* __restrict__ features,
                                                   float* __restrict__ xT,
                                                   float* __restrict__ hT,
                                                   float* __restrict__ cT) {
    int g = blockIdx.x * 256 + threadIdx.x;   // 0..65535
    int j = g >> 7, b = g & 127;
    xT[g] = features[b * E + j];
    hT[g] = 0.0f;
    cT[g] = 0.0f;
}

// ---- gates GEMM (fp32, unchanged from R2): pT[ks][n][b] --------------------
__global__ __launch_bounds__(256) void gates_kernel(const float* __restrict__ xT,
                                                    const float* __restrict__ hT,
                                                    const float* __restrict__ W_ih,
                                                    const float* __restrict__ W_hh,
                                                    float* __restrict__ pT) {
    const int ntile = blockIdx.x;   // 0..15 (128 n each)
    const int ks = blockIdx.y;      // 0..15 (64 k each)
    const int tid = threadIdx.x;
    const int nt = tid & 15;        // n0 = nt*8
    const int bt = tid >> 4;        // b0 = bt*8
    __shared__ float xs[64][128];
    __shared__ float ws[128][64];
    const int kb = ks * 64;
    const bool isX = kb < E;
    const float* __restrict__ src = isX ? (xT + (size_t)kb * B) : (hT + (size_t)(kb - E) * B);
#pragma unroll
    for (int i = 0; i < 8; ++i) {
        int flat = i * 256 + tid;
        int kk = flat >> 5, b4 = flat & 31;
        *reinterpret_cast<float4*>(&xs[kk][b4 * 4]) =
            *reinterpret_cast<const float4*>(src + kk * B + b4 * 4);
    }
    {
        int r = tid >> 1, kh = tid & 1;
        int nglob = ntile * 128 + r;
        int jrow = nglob >> 2, g = nglob & 3;
        const float* __restrict__ Wp = isX ? (W_ih + (size_t)(g * H + jrow) * E + kb)
                                           : (W_hh + (size_t)(g * H + jrow) * H + (kb - E));
#pragma unroll
        for (int c = 0; c < 8; ++c) {
            int slot = (kh * 8 + c) ^ (r >> 3);
            *reinterpret_cast<float4*>(&ws[r][slot * 4]) =
                *reinterpret_cast<const float4*>(Wp + kh * 32 + c * 4);
        }
    }
    __syncthreads();
    float acc[8][8];
#pragma unroll
    for (int i = 0; i < 8; ++i)
#pragma unroll
        for (int j = 0; j < 8; ++j) acc[i][j] = 0.0f;

    for (int k4 = 0; k4 < 16; ++k4) {
        float wr[8][4];
#pragma unroll
        for (int ni = 0; ni < 8; ++ni) {
            int slot = k4 ^ nt;
            *reinterpret_cast<float4*>(wr[ni]) =
                *reinterpret_cast<const float4*>(&ws[nt * 8 + ni][slot * 4]);
        }
#pragma unroll
        for (int kk = 0; kk < 4; ++kk) {
            int k = k4 * 4 + kk;
            float4 x0 = *reinterpret_cast<const float4*>(&xs[k][bt * 8]);
            float4 x1 = *reinterpret_cast<const float4*>(&xs[k][bt * 8 + 4]);
            float xr[8] = {x0.x, x0.y, x0.z, x0.w, x1.x, x1.y, x1.z, x1.w};
#pragma unroll
            for (int bi = 0; bi < 8; ++bi)
#pragma unroll
                for (int ni = 0; ni < 8; ++ni) acc[bi][ni] += xr[bi] * wr[ni][kk];
        }
    }
#pragma unroll
    for (int ni = 0; ni < 8; ++ni) {
        size_t n = (size_t)ks * NG + ntile * 128 + nt * 8 + ni;
#pragma unroll
        for (int b4 = 0; b4 < 2; ++b4) {
            float4 col = make_float4(acc[b4 * 4 + 0][ni], acc[b4 * 4 + 1][ni],
                                     acc[b4 * 4 + 2][ni], acc[b4 * 4 + 3][ni]);
            *reinterpret_cast<float4*>(&pT[n * B + bt * 8 + b4 * 4]) = col;
        }
    }
}

// ---- LSTM cell (R2 + h_bk emit) --------------------------------------------
__global__ __launch_bounds__(256) void cell_kernel(const float* __restrict__ pT,
                                                   const float* __restrict__ b_ih,
                                                   const float* __restrict__ b_hh,
                                                   float* __restrict__ cT,
                                                   float* __restrict__ hT,
                                                   short* __restrict__ h_hi,
                                                   short* __restrict__ h_lo,
                                                   float* __restrict__ h_bk) {
    int tid = threadIdx.x;
    int b = tid & 127;
    int j = blockIdx.x * 2 + (tid >> 7);
    float gs[4];
#pragma unroll
    for (int g = 0; g < 4; ++g) {
        float s = b_ih[g * H + j] + b_hh[g * H + j];
#pragma unroll
        for (int ks = 0; ks < KSPLIT; ++ks) s += pT[((size_t)ks * NG + 4 * j + g) * B + b];
        gs[g] = s;
    }
    float ig = sigmoidf_(gs[0]);
    float fg = sigmoidf_(gs[1]);
    float gg = tanhf(gs[2]);
    float og = sigmoidf_(gs[3]);
    float c = fg * cT[j * B + b] + ig * gg;
    cT[j * B + b] = c;
    float h = og * tanhf(c);
    hT[j * B + b] = h;
    h_bk[b * 512 + j] = h;
    short hs = f2bf_s(h);
    h_hi[b * 512 + j] = hs;
    h_lo[b * 512 + j] = f2bf_s(h - bfs2f(hs));
}

// ---- logits via MFMA (split bf16, packed W) + per-block top-2 --------------
// 512 thr / 8 waves; M=128(all b) x N=128 per block. Waves 0-3 compute 32 n
// each (2 16-n tiles); all 8 stage h with register prefetch. Per-(b,block)
// top-2 keys merged in LDS, written pk[b][bid] (coalesced for argmax).
__global__ __launch_bounds__(512) void logits_kernel(const short* __restrict__ h_hi,
                                                     const short* __restrict__ h_lo,
                                                     const short* __restrict__ Wph,
                                                     const short* __restrict__ Wpl,
                                                     const float* __restrict__ b_fc,
                                                     ull* __restrict__ pk1,
                                                     ull* __restrict__ pk2) {
    const int bid = blockIdx.x;          // 0..249
    const int tid = threadIdx.x;
    const int w = tid >> 6;              // wave 0..7; 0-3 compute
    const int l = tid & 63;
    const int l15 = l & 15, lg = l >> 4;
    __shared__ union {
        short lh[2][128 * 64];                       // 32 KB, swizzled 16B slots
        struct { ull a1[4][128]; ull a2[4][128]; } ep;
    } sm;
    f32x4 acc[8][2];
#pragma unroll
    for (int mt = 0; mt < 8; ++mt)
#pragma unroll
        for (int ns = 0; ns < 2; ++ns) acc[mt][ns] = (f32x4){0.f, 0.f, 0.f, 0.f};

    // register-prefetch staging state (2 slots per thread, hi+lo)
    short8v ph[2], pl[2];
    {
#pragma unroll
        for (int i = 0; i < 2; ++i) {
            int flat = tid + i * 512;
            int row = flat >> 3, c = flat & 7;
            ph[i] = *reinterpret_cast<const short8v*>(&h_hi[row * 512 + c * 8]);
            pl[i] = *reinterpret_cast<const short8v*>(&h_lo[row * 512 + c * 8]);
        }
    }
    for (int cc = 0; cc < 8; ++cc) {
        __syncthreads();
#pragma unroll
        for (int i = 0; i < 2; ++i) {
            int flat = tid + i * 512;
            int row = flat >> 3, c = flat & 7;
            int dst = row * 64 + ((c ^ (row & 7)) << 3);
            *reinterpret_cast<short8v*>(&sm.lh[0][dst]) = ph[i];
            *reinterpret_cast<short8v*>(&sm.lh[1][dst]) = pl[i];
        }
        __syncthreads();
        if (cc < 7) {
            const int kb = (cc + 1) * 64;
#pragma unroll
            for (int i = 0; i < 2; ++i) {
                int flat = tid + i * 512;
                int row = flat >> 3, c = flat & 7;
                ph[i] = *reinterpret_cast<const short8v*>(&h_hi[row * 512 + kb + c * 8]);
                pl[i] = *reinterpret_cast<const short8v*>(&h_lo[row * 512 + kb + c * 8]);
            }
        }
        if (w < 4) {
            short8v bh[2][2], bl[2][2];
#pragma unroll
            for (int ns = 0; ns < 2; ++ns) {
                int nt = bid * 8 + w * 2 + ns;
#pragma unroll
                for (int ks2 = 0; ks2 < 2; ++ks2) {
                    size_t off = ((((size_t)nt * 8 + cc) * 2 + ks2) * 64 + l) * 8;
                    bh[ns][ks2] = *reinterpret_cast<const short8v*>(&Wph[off]);
                    bl[ns][ks2] = *reinterpret_cast<const short8v*>(&Wpl[off]);
                }
            }
#pragma unroll
            for (int ks2 = 0; ks2 < 2; ++ks2) {
#pragma unroll
                for (int mt = 0; mt < 8; ++mt) {
                    int row = mt * 16 + l15;
                    int cslot = ks2 * 4 + lg;
                    int off = row * 64 + ((cslot ^ (row & 7)) << 3);
                    short8v ah = *reinterpret_cast<const short8v*>(&sm.lh[0][off]);
                    short8v al = *reinterpret_cast<const short8v*>(&sm.lh[1][off]);
#pragma unroll
                    for (int ns = 0; ns < 2; ++ns) {
                        acc[mt][ns] = __builtin_amdgcn_mfma_f32_16x16x32_bf16(ah, bh[ns][ks2], acc[mt][ns], 0, 0, 0);
                        acc[mt][ns] = __builtin_amdgcn_mfma_f32_16x16x32_bf16(ah, bl[ns][ks2], acc[mt][ns], 0, 0, 0);
                        acc[mt][ns] = __builtin_amdgcn_mfma_f32_16x16x32_bf16(al, bh[ns][ks2], acc[mt][ns], 0, 0, 0);
                    }
                }
            }
        }
    }
    __syncthreads();   // lh done; switch union to ep
    if (w < 4) {
        const int nr0 = bid * 128 + w * 32 + l15;
        const int nr1 = nr0 + 16;
        const float bias0 = b_fc[nr0];
        const float bias1 = b_fc[nr1];
#pragma unroll
        for (int mt = 0; mt < 8; ++mt) {
#pragma unroll
            for (int r = 0; r < 4; ++r) {
                ull k1 = makekey(acc[mt][0][r] + bias0, (unsigned)nr0);
                ull k2 = 0;
                merge2(k1, k2, makekey(acc[mt][1][r] + bias1, (unsigned)nr1), 0);
#pragma unroll
                for (int off = 1; off < 16; off <<= 1) {
                    ull o1 = shflx_u64(k1, off);
                    ull o2 = shflx_u64(k2, off);
                    merge2(k1, k2, o1, o2);
                }
                if (l15 == 0) {
                    int brow = mt * 16 + lg * 4 + r;
                    sm.ep.a1[w][brow] = k1;
                    sm.ep.a2[w][brow] = k2;
                }
            }
        }
    }
    __syncthreads();
    if (tid < 128) {
        ull k1 = sm.ep.a1[0][tid], k2 = sm.ep.a2[0][tid];
#pragma unroll
        for (int wv = 1; wv < 4; ++wv) merge2(k1, k2, sm.ep.a1[wv][tid], sm.ep.a2[wv][tid]);
        pk1[(size_t)tid * PKPAD + bid] = k1;
        pk2[(size_t)tid * PKPAD + bid] = k2;
    }
}

// ---- final: global top-2 -> exact fp32 recompute -> outputs + gather -------
__global__ __launch_bounds__(256) void argmax_kernel(const ull* __restrict__ pk1,
                                                     const ull* __restrict__ pk2,
                                                     const float* __restrict__ h_bk,
                                                     const float* __restrict__ W_fc,
                                                     const float* __restrict__ b_fc,
                                                     const float* __restrict__ emb,
                                                     float* __restrict__ xT,
                                                     float* __restrict__ out,
                                                     int t) {
    const int b = blockIdx.x;
    const int tid = threadIdx.x;
    ull k1 = 0, k2 = 0;
    if (tid < NBLK_L) {
        k1 = pk1[(size_t)b * PKPAD + tid];
        k2 = pk2[(size_t)b * PKPAD + tid];
    }
#pragma unroll
    for (int off = 1; off < 64; off <<= 1)
        merge2(k1, k2, shflx_u64(k1, off), shflx_u64(k2, off));
    __shared__ ull sk1[4], sk2[4];
    __shared__ float part[4];
    __shared__ int s_i1, s_i2, s_w;
    if ((tid & 63) == 0) { sk1[tid >> 6] = k1; sk2[tid >> 6] = k2; }
    __syncthreads();
    if (tid == 0) {
        k1 = sk1[0]; k2 = sk2[0];
#pragma unroll
        for (int wv = 1; wv < 4; ++wv) merge2(k1, k2, sk1[wv], sk2[wv]);
        s_i1 = keyidx(k1);
        s_i2 = keyidx(k2);
    }
    __syncthreads();
    const int i1 = s_i1, i2 = s_i2;
    // exact fp32 dots for both candidates (same tree as R2: absmax 0.0)
    const int wv = tid >> 6, l = tid & 63;
    const int idx = (wv >> 1) ? i2 : i1;
    const int k0 = (wv & 1) * 256 + l * 4;
    float4 hv = *reinterpret_cast<const float4*>(&h_bk[(size_t)b * 512 + k0]);
    float4 wf = *reinterpret_cast<const float4*>(&W_fc[(size_t)idx * E + k0]);
    float hr[4] = {hv.x, hv.y, hv.z, hv.w};
    float wr[4] = {wf.x, wf.y, wf.z, wf.w};
    float s = 0.0f;
#pragma unroll
    for (int kk = 0; kk < 4; ++kk) s += hr[kk] * wr[kk];
#pragma unroll
    for (int off = 1; off < 64; off <<= 1) s += __shfl_xor(s, off);
    if (l == 0) part[wv] = s;
    __syncthreads();
    if (tid == 0) {
        float v0 = part[0] + part[1] + b_fc[i1];
        float v1 = part[2] + part[3] + b_fc[i2];
        int wi; float wvv;
        if (v1 > v0 || (v1 == v0 && i2 < i1)) { wi = i2; wvv = v1; }
        else { wi = i1; wvv = v0; }
        out[b * TSEQ + t] = (float)wi;
        out[B * TSEQ + b * TSEQ + t] = wvv;
        s_w = wi;
    }
    __syncthreads();
    const int widx = s_w;
    xT[(size_t)tid * B + b] = emb[(size_t)widx * E + tid];
    xT[(size_t)(tid + 256) * B + b] = emb[(size_t)widx * E + tid + 256];
}

// ============================================================================
extern "C" void kernel_launch(void* const* d_in, const int* in_sizes, int n_in,
                              void* d_out, int out_size, void* d_ws, size_t ws_size,
                              hipStream_t stream) {
    const float* features = (const float*)d_in[0];
    // d_in[1] = lengths: unused (fixed-length scan)
    const float* emb  = (const float*)d_in[2];
    const float* W_ih = (const float*)d_in[3];
    const float* W_hh = (const float*)d_in[4];
    const float* b_ih = (const float*)d_in[5];
    const float* b_hh = (const float*)d_in[6];
    const float* W_fc = (const float*)d_in[7];
    const float* b_fc = (const float*)d_in[8];
    float* out = (float*)d_out;

    char* p = (char*)d_ws;                   // ~84 MB total (ws is ~268 MB)
    short* Wph = (short*)p;       p += (size_t)V * E * 2;        // 32.77 MB
    short* Wpl = (short*)p;       p += (size_t)V * E * 2;        // 32.77 MB
    ull* pk1 = (ull*)p;           p += (size_t)B * PKPAD * 8;    // 256 KB
    ull* pk2 = (ull*)p;           p += (size_t)B * PKPAD * 8;    // 256 KB
    float* xT = (float*)p;        p += (size_t)E * B * 4;
    float* hT = (float*)p;        p += (size_t)E * B * 4;
    float* cT = (float*)p;        p += (size_t)E * B * 4;
    float* pT = (float*)p;        p += (size_t)KSPLIT * NG * B * 4;  // 16.78 MB
    short* h_hi = (short*)p;      p += (size_t)E * B * 2;
    short* h_lo = (short*)p;      p += (size_t)E * B * 2;
    float* h_bk = (float*)p;      p += (size_t)E * B * 4;

    wsplit_pack_kernel<<<8000, 256, 0, stream>>>(W_fc, Wph, Wpl);
    init_kernel<<<256, 256, 0, stream>>>(features, xT, hT, cT);
    for (int t = 0; t < TSEQ; ++t) {
        gates_kernel<<<dim3(16, 16), 256, 0, stream>>>(xT, hT, W_ih, W_hh, pT);
        cell_kernel<<<256, 256, 0, stream>>>(pT, b_ih, b_hh, cT, hT, h_hi, h_lo, h_bk);
        logits_kernel<<<NBLK_L, 512, 0, stream>>>(h_hi, h_lo, Wph, Wpl, b_fc, pk1, pk2);
        argmax_kernel<<<B, 256, 0, stream>>>(pk1, pk2, h_bk, W_fc, b_fc, emb, xT, out, t);
    }
}

// Round 7
// 1168.631 us; speedup vs baseline: 4.1817x; 1.1100x over previous
//
#include <hip/hip_runtime.h>
#include <hip/hip_bf16.h>
#include <math.h>

// LSTM greedy decoder — R5 (resubmitted in R6; prior bench never acquired a GPU).
//  - gates/cell: fp32, summation tree UNCHANGED since R2 (h bit-exact, vals
//    absmax 0.0 twice) — do not touch.
//  - logits: pure bf16 MFMA (1 term, was 3-term hi/lo split). Decision safety
//    now via global top-4 candidates + exact fp32 recompute (R4's exact tree,
//    bit-identical). sigma(logit)~1.6e-3 << top-gap ~0.07 -> P(miss)<1e-6.
//    Halves W traffic (32.7MB/step), 3x fewer MFMAs, halves LDS A-reads.
//  - wsplit: output-slot-owned mapping -> fully coalesced 16B writes,
//    128B-segment gather reads; hi only (57us -> ~18us predicted).

#define B 128
#define E 512
#define H 512
#define V 32000
#define TSEQ 20
#define NG 2048            // 4*H
#define KSPLIT 16
#define NBLK_L 250         // 32000 / 128
#define PKPAD 256          // padded per-b partial count (250 used)

typedef __attribute__((ext_vector_type(8))) short short8v;
typedef __attribute__((ext_vector_type(4))) float f32x4;
typedef unsigned long long ull;

__device__ __forceinline__ float sigmoidf_(float x) { return 1.0f / (1.0f + expf(-x)); }

__device__ __forceinline__ short f2bf_s(float x) {
    __hip_bfloat16 h = __float2bfloat16(x);
    return *reinterpret_cast<short*>(&h);
}
__device__ __forceinline__ ull shflx_u64(ull x, int m) {
    int lo = __shfl_xor((int)(unsigned int)x, m);
    int hi = __shfl_xor((int)(unsigned int)(x >> 32), m);
    return ((ull)(unsigned int)hi << 32) | (unsigned int)lo;
}
// keep (k1,k2) = top-2 keys; merge with another sorted pair (o1,o2)
__device__ __forceinline__ void merge2(ull& k1, ull& k2, ull o1, ull o2) {
    ull a = k1 > o1 ? k1 : o1;
    ull b = k1 > o1 ? o1 : k1;
    ull c = k2 > o2 ? k2 : o2;
    k1 = a;
    k2 = b > c ? b : c;
}
// branchless merge of two sorted-desc quads -> top-4 sorted-desc into q
__device__ __forceinline__ void mergeQ(ull q[4], const ull o[4]) {
    ull a0 = q[0], a1 = q[1], a2 = q[2], a3 = q[3];
    ull b0 = o[0], b1 = o[1], b2 = o[2], b3 = o[3];
    ull r[4];
#pragma unroll
    for (int i = 0; i < 4; ++i) {
        bool t = a0 >= b0;
        r[i] = t ? a0 : b0;
        ull na0 = t ? a1 : a0, na1 = t ? a2 : a1, na2 = t ? a3 : a2, na3 = t ? 0ull : a3;
        ull nb0 = t ? b0 : b1, nb1 = t ? b1 : b2, nb2 = t ? b2 : b3, nb3 = t ? b3 : 0ull;
        a0 = na0; a1 = na1; a2 = na2; a3 = na3;
        b0 = nb0; b1 = nb1; b2 = nb2; b3 = nb3;
    }
    q[0] = r[0]; q[1] = r[1]; q[2] = r[2]; q[3] = r[3];
}
// sortable key: high 32 = monotonic float bits, low 32 = ~n (max v, then min n)
__device__ __forceinline__ ull makekey(float v, unsigned int n) {
    unsigned int u = __float_as_uint(v);
    u ^= (unsigned int)(((int)u >> 31)) | 0x80000000u;
    return ((ull)u << 32) | (0xFFFFFFFFu - n);
}
__device__ __forceinline__ int keyidx(ull k) {
    return (int)(0xFFFFFFFFu - (unsigned int)(k & 0xFFFFFFFFu));
}

// ---- W_fc fp32 -> packed bf16 (hi only), output-slot-owned -----------------
// slot s (16B of 8 bf16): lane=s&63 (l15=lane&15,lg=lane>>4), ks2=(s>>6)&1,
// cc=(s>>7)&7, nt=s>>10; n=nt*16+l15, k=cc*64+ks2*32+lg*8.
// Writes: thread-consecutive 16B (perfect). Reads: per 64 threads, 16 rows x
// 128B contiguous segments (good).
__global__ __launch_bounds__(256) void wsplit_pack_kernel(const float* __restrict__ W,
                                                          short* __restrict__ Wph) {
    unsigned s = blockIdx.x * 256 + threadIdx.x;      // 0..2,047,999
    int lane = s & 63, l15 = lane & 15, lg = lane >> 4;
    int ks2 = (s >> 6) & 1, cc = (s >> 7) & 7, nt = s >> 10;
    int n = nt * 16 + l15;
    int k = cc * 64 + ks2 * 32 + lg * 8;
    const float* __restrict__ src = W + (size_t)n * E + k;
    float4 a = *reinterpret_cast<const float4*>(src);
    float4 b = *reinterpret_cast<const float4*>(src + 4);
    float xv[8] = {a.x, a.y, a.z, a.w, b.x, b.y, b.z, b.w};
    union { short8v v; short sh[8]; } uh;
#pragma unroll
    for (int j = 0; j < 8; ++j) uh.sh[j] = f2bf_s(xv[j]);
    *reinterpret_cast<short8v*>(Wph + (size_t)s * 8) = uh.v;
}

// ---- init: features -> xT (transposed), zero hT/cT -------------------------
__global__ __launch_bounds__(256) void init_kernel(const float* __restrict__ features,
                                                   float* __restrict__ xT,
                                                   float* __restrict__ hT,
                                                   float* __restrict__ cT) {
    int g = blockIdx.x * 256 + threadIdx.x;   // 0..65535
    int j = g >> 7, b = g & 127;
    xT[g] = features[b * E + j];
    hT[g] = 0.0f;
    cT[g] = 0.0f;
}

// ---- gates GEMM (fp32, unchanged since R2): pT[ks][n][b] -------------------
__global__ __launch_bounds__(256) void gates_kernel(const float* __restrict__ xT,
                                                    const float* __restrict__ hT,
                                                    const float* __restrict__ W_ih,
                                                    const float* __restrict__ W_hh,
                                                    float* __restrict__ pT) {
    const int ntile = blockIdx.x;   // 0..15 (128 n each)
    const int ks = blockIdx.y;      // 0..15 (64 k each)
    const int tid = threadIdx.x;
    const int nt = tid & 15;        // n0 = nt*8
    const int bt = tid >> 4;        // b0 = bt*8
    __shared__ float xs[64][128];
    __shared__ float ws[128][64];
    const int kb = ks * 64;
    const bool isX = kb < E;
    const float* __restrict__ src = isX ? (xT + (size_t)kb * B) : (hT + (size_t)(kb - E) * B);
#pragma unroll
    for (int i = 0; i < 8; ++i) {
        int flat = i * 256 + tid;
        int kk = flat >> 5, b4 = flat & 31;
        *reinterpret_cast<float4*>(&xs[kk][b4 * 4]) =
            *reinterpret_cast<const float4*>(src + kk * B + b4 * 4);
    }
    {
        int r = tid >> 1, kh = tid & 1;
        int nglob = ntile * 128 + r;
        int jrow = nglob >> 2, g = nglob & 3;
        const float* __restrict__ Wp = isX ? (W_ih + (size_t)(g * H + jrow) * E + kb)
                                           : (W_hh + (size_t)(g * H + jrow) * H + (kb - E));
#pragma unroll
        for (int c = 0; c < 8; ++c) {
            int slot = (kh * 8 + c) ^ (r >> 3);
            *reinterpret_cast<float4*>(&ws[r][slot * 4]) =
                *reinterpret_cast<const float4*>(Wp + kh * 32 + c * 4);
        }
    }
    __syncthreads();
    float acc[8][8];
#pragma unroll
    for (int i = 0; i < 8; ++i)
#pragma unroll
        for (int j = 0; j < 8; ++j) acc[i][j] = 0.0f;

    for (int k4 = 0; k4 < 16; ++k4) {
        float wr[8][4];
#pragma unroll
        for (int ni = 0; ni < 8; ++ni) {
            int slot = k4 ^ nt;
            *reinterpret_cast<float4*>(wr[ni]) =
                *reinterpret_cast<const float4*>(&ws[nt * 8 + ni][slot * 4]);
        }
#pragma unroll
        for (int kk = 0; kk < 4; ++kk) {
            int k = k4 * 4 + kk;
            float4 x0 = *reinterpret_cast<const float4*>(&xs[k][bt * 8]);
            float4 x1 = *reinterpret_cast<const float4*>(&xs[k][bt * 8 + 4]);
            float xr[8] = {x0.x, x0.y, x0.z, x0.w, x1.x, x1.y, x1.z, x1.w};
#pragma unroll
            for (int bi = 0; bi < 8; ++bi)
#pragma unroll
                for (int ni = 0; ni < 8; ++ni) acc[bi][ni] += xr[bi] * wr[ni][kk];
        }
    }
#pragma unroll
    for (int ni = 0; ni < 8; ++ni) {
        size_t n = (size_t)ks * NG + ntile * 128 + nt * 8 + ni;
#pragma unroll
        for (int b4 = 0; b4 < 2; ++b4) {
            float4 col = make_float4(acc[b4 * 4 + 0][ni], acc[b4 * 4 + 1][ni],
                                     acc[b4 * 4 + 2][ni], acc[b4 * 4 + 3][ni]);
            *reinterpret_cast<float4*>(&pT[n * B + bt * 8 + b4 * 4]) = col;
        }
    }
}

// ---- LSTM cell (fp32 tree unchanged; h_lo dropped) -------------------------
__global__ __launch_bounds__(256) void cell_kernel(const float* __restrict__ pT,
                                                   const float* __restrict__ b_ih,
                                                   const float* __restrict__ b_hh,
                                                   float* __restrict__ cT,
                                                   float* __restrict__ hT,
                                                   short* __restrict__ h_hi,
                                                   float* __restrict__ h_bk) {
    int tid = threadIdx.x;
    int b = tid & 127;
    int j = blockIdx.x * 2 + (tid >> 7);
    float gs[4];
#pragma unroll
    for (int g = 0; g < 4; ++g) {
        float s = b_ih[g * H + j] + b_hh[g * H + j];
#pragma unroll
        for (int ks = 0; ks < KSPLIT; ++ks) s += pT[((size_t)ks * NG + 4 * j + g) * B + b];
        gs[g] = s;
    }
    float ig = sigmoidf_(gs[0]);
    float fg = sigmoidf_(gs[1]);
    float gg = tanhf(gs[2]);
    float og = sigmoidf_(gs[3]);
    float c = fg * cT[j * B + b] + ig * gg;
    cT[j * B + b] = c;
    float h = og * tanhf(c);
    hT[j * B + b] = h;
    h_bk[b * 512 + j] = h;
    h_hi[b * 512 + j] = f2bf_s(h);
}

// ---- logits: pure bf16 MFMA + per-block top-2 keys -------------------------
// 512 thr / 8 waves; M=128(all b) x N=128 per block. Waves 0-3 compute 32 n
// each; all 8 stage h (register prefetch). Per-block top-2 -> pk[b][bid].
__global__ __launch_bounds__(512) void logits_kernel(const short* __restrict__ h_hi,
                                                     const short* __restrict__ Wph,
                                                     const float* __restrict__ b_fc,
                                                     ull* __restrict__ pk1,
                                                     ull* __restrict__ pk2) {
    const int bid = blockIdx.x;          // 0..249
    const int tid = threadIdx.x;
    const int w = tid >> 6;              // wave 0..7; 0-3 compute
    const int l = tid & 63;
    const int l15 = l & 15, lg = l >> 4;
    __shared__ union {
        short lh[128 * 64];                          // 16 KB, swizzled 16B slots
        struct { ull a1[4][128]; ull a2[4][128]; } ep;
    } sm;
    f32x4 acc[8][2];
#pragma unroll
    for (int mt = 0; mt < 8; ++mt)
#pragma unroll
        for (int ns = 0; ns < 2; ++ns) acc[mt][ns] = (f32x4){0.f, 0.f, 0.f, 0.f};

    short8v ph[2];
#pragma unroll
    for (int i = 0; i < 2; ++i) {
        int flat = tid + i * 512;
        int row = flat >> 3, c = flat & 7;
        ph[i] = *reinterpret_cast<const short8v*>(&h_hi[row * 512 + c * 8]);
    }
    for (int cc = 0; cc < 8; ++cc) {
        __syncthreads();
#pragma unroll
        for (int i = 0; i < 2; ++i) {
            int flat = tid + i * 512;
            int row = flat >> 3, c = flat & 7;
            int dst = row * 64 + ((c ^ (row & 7)) << 3);
            *reinterpret_cast<short8v*>(&sm.lh[dst]) = ph[i];
        }
        __syncthreads();
        if (cc < 7) {
            const int kb = (cc + 1) * 64;
#pragma unroll
            for (int i = 0; i < 2; ++i) {
                int flat = tid + i * 512;
                int row = flat >> 3, c = flat & 7;
                ph[i] = *reinterpret_cast<const short8v*>(&h_hi[row * 512 + kb + c * 8]);
            }
        }
        if (w < 4) {
            short8v bh[2][2];
#pragma unroll
            for (int ns = 0; ns < 2; ++ns) {
                int nt = bid * 8 + w * 2 + ns;
#pragma unroll
                for (int ks2 = 0; ks2 < 2; ++ks2) {
                    size_t off = ((((size_t)nt * 8 + cc) * 2 + ks2) * 64 + l) * 8;
                    bh[ns][ks2] = *reinterpret_cast<const short8v*>(&Wph[off]);
                }
            }
#pragma unroll
            for (int ks2 = 0; ks2 < 2; ++ks2) {
#pragma unroll
                for (int mt = 0; mt < 8; ++mt) {
                    int row = mt * 16 + l15;
                    int cslot = ks2 * 4 + lg;
                    int off = row * 64 + ((cslot ^ (row & 7)) << 3);
                    short8v ah = *reinterpret_cast<const short8v*>(&sm.lh[off]);
#pragma unroll
                    for (int ns = 0; ns < 2; ++ns)
                        acc[mt][ns] = __builtin_amdgcn_mfma_f32_16x16x32_bf16(ah, bh[ns][ks2], acc[mt][ns], 0, 0, 0);
                }
            }
        }
    }
    __syncthreads();   // lh done; switch union to ep
    if (w < 4) {
        const int nr0 = bid * 128 + w * 32 + l15;
        const int nr1 = nr0 + 16;
        const float bias0 = b_fc[nr0];
        const float bias1 = b_fc[nr1];
#pragma unroll
        for (int mt = 0; mt < 8; ++mt) {
#pragma unroll
            for (int r = 0; r < 4; ++r) {
                ull k1 = makekey(acc[mt][0][r] + bias0, (unsigned)nr0);
                ull k2 = 0;
                merge2(k1, k2, makekey(acc[mt][1][r] + bias1, (unsigned)nr1), 0);
#pragma unroll
                for (int off = 1; off < 16; off <<= 1) {
                    ull o1 = shflx_u64(k1, off);
                    ull o2 = shflx_u64(k2, off);
                    merge2(k1, k2, o1, o2);
                }
                if (l15 == 0) {
                    int brow = mt * 16 + lg * 4 + r;
                    sm.ep.a1[w][brow] = k1;
                    sm.ep.a2[w][brow] = k2;
                }
            }
        }
    }
    __syncthreads();
    if (tid < 128) {
        ull k1 = sm.ep.a1[0][tid], k2 = sm.ep.a2[0][tid];
#pragma unroll
        for (int wv = 1; wv < 4; ++wv) merge2(k1, k2, sm.ep.a1[wv][tid], sm.ep.a2[wv][tid]);
        pk1[(size_t)tid * PKPAD + bid] = k1;
        pk2[(size_t)tid * PKPAD + bid] = k2;
    }
}

// ---- final: global top-4 -> exact fp32 recompute (R4 tree x2) --------------
__global__ __launch_bounds__(256) void argmax_kernel(const ull* __restrict__ pk1,
                                                     const ull* __restrict__ pk2,
                                                     const float* __restrict__ h_bk,
                                                     const float* __restrict__ W_fc,
                                                     const float* __restrict__ b_fc,
                                                     const float* __restrict__ emb,
                                                     float* __restrict__ xT,
                                                     float* __restrict__ out,
                                                     int t) {
    const int b = blockIdx.x;
    const int tid = threadIdx.x;
    ull q[4] = {0, 0, 0, 0};
    if (tid < NBLK_L) {
        q[0] = pk1[(size_t)b * PKPAD + tid];
        q[1] = pk2[(size_t)b * PKPAD + tid];
    }
#pragma unroll
    for (int off = 1; off < 64; off <<= 1) {
        ull oq[4];
#pragma unroll
        for (int j = 0; j < 4; ++j) oq[j] = shflx_u64(q[j], off);
        mergeQ(q, oq);
    }
    __shared__ ull skq[4][4];
    __shared__ float vex[4];
    __shared__ int s_idx[4];
    __shared__ float part[4];
    __shared__ int s_w;
    if ((tid & 63) == 0) {
#pragma unroll
        for (int j = 0; j < 4; ++j) skq[tid >> 6][j] = q[j];
    }
    __syncthreads();
    if (tid == 0) {
#pragma unroll
        for (int j = 0; j < 4; ++j) q[j] = skq[0][j];
#pragma unroll
        for (int wv = 1; wv < 4; ++wv) mergeQ(q, skq[wv]);
#pragma unroll
        for (int j = 0; j < 4; ++j) s_idx[j] = keyidx(q[j]);
    }
    __syncthreads();
    // two passes of the exact R4 recompute tree (bitwise-preserving)
    const int wv = tid >> 6, l = tid & 63;
#pragma unroll
    for (int pass = 0; pass < 2; ++pass) {
        const int i1 = s_idx[pass * 2], i2 = s_idx[pass * 2 + 1];
        const int idx = (wv >> 1) ? i2 : i1;
        const int k0 = (wv & 1) * 256 + l * 4;
        float4 hv = *reinterpret_cast<const float4*>(&h_bk[(size_t)b * 512 + k0]);
        float4 wf = *reinterpret_cast<const float4*>(&W_fc[(size_t)idx * E + k0]);
        float hr[4] = {hv.x, hv.y, hv.z, hv.w};
        float wr[4] = {wf.x, wf.y, wf.z, wf.w};
        float s = 0.0f;
#pragma unroll
        for (int kk = 0; kk < 4; ++kk) s += hr[kk] * wr[kk];
#pragma unroll
        for (int off = 1; off < 64; off <<= 1) s += __shfl_xor(s, off);
        if (l == 0) part[wv] = s;
        __syncthreads();
        if (tid == 0) {
            vex[pass * 2]     = part[0] + part[1] + b_fc[i1];
            vex[pass * 2 + 1] = part[2] + part[3] + b_fc[i2];
        }
        __syncthreads();
    }
    if (tid == 0) {
        int wi = s_idx[0];
        float wvv = vex[0];
#pragma unroll
        for (int c = 1; c < 4; ++c) {
            float v = vex[c];
            int ii = s_idx[c];
            if (v > wvv || (v == wvv && ii < wi)) { wvv = v; wi = ii; }
        }
        out[b * TSEQ + t] = (float)wi;
        out[B * TSEQ + b * TSEQ + t] = wvv;
        s_w = wi;
    }
    __syncthreads();
    const int widx = s_w;
    xT[(size_t)tid * B + b] = emb[(size_t)widx * E + tid];
    xT[(size_t)(tid + 256) * B + b] = emb[(size_t)widx * E + tid + 256];
}

// ============================================================================
extern "C" void kernel_launch(void* const* d_in, const int* in_sizes, int n_in,
                              void* d_out, int out_size, void* d_ws, size_t ws_size,
                              hipStream_t stream) {
    const float* features = (const float*)d_in[0];
    // d_in[1] = lengths: unused (fixed-length scan)
    const float* emb  = (const float*)d_in[2];
    const float* W_ih = (const float*)d_in[3];
    const float* W_hh = (const float*)d_in[4];
    const float* b_ih = (const float*)d_in[5];
    const float* b_hh = (const float*)d_in[6];
    const float* W_fc = (const float*)d_in[7];
    const float* b_fc = (const float*)d_in[8];
    float* out = (float*)d_out;

    char* p = (char*)d_ws;                   // ~52 MB total
    short* Wph = (short*)p;       p += (size_t)V * E * 2;        // 32.77 MB
    ull* pk1 = (ull*)p;           p += (size_t)B * PKPAD * 8;    // 256 KB
    ull* pk2 = (ull*)p;           p += (size_t)B * PKPAD * 8;    // 256 KB
    float* xT = (float*)p;        p += (size_t)E * B * 4;
    float* hT = (float*)p;        p += (size_t)E * B * 4;
    float* cT = (float*)p;        p += (size_t)E * B * 4;
    float* pT = (float*)p;        p += (size_t)KSPLIT * NG * B * 4;  // 16.78 MB
    short* h_hi = (short*)p;      p += (size_t)E * B * 2;
    float* h_bk = (float*)p;      p += (size_t)E * B * 4;

    wsplit_pack_kernel<<<8000, 256, 0, stream>>>(W_fc, Wph);
    init_kernel<<<256, 256, 0, stream>>>(features, xT, hT, cT);
    for (int t = 0; t < TSEQ; ++t) {
        gates_kernel<<<dim3(16, 16), 256, 0, stream>>>(xT, hT, W_ih, W_hh, pT);
        cell_kernel<<<256, 256, 0, stream>>>(pT, b_ih, b_hh, cT, hT, h_hi, h_bk);
        logits_kernel<<<NBLK_L, 512, 0, stream>>>(h_hi, Wph, b_fc, pk1, pk2);
        argmax_kernel<<<B, 256, 0, stream>>>(pk1, pk2, h_bk, W_fc, b_fc, emb, xT, out, t);
    }
}